// Round 2
// baseline (1058.316 us; speedup 1.0000x reference)
//
#include <hip/hip_runtime.h>

typedef __attribute__((ext_vector_type(8))) short short8;
typedef __attribute__((ext_vector_type(4))) float f32x4;
typedef __attribute__((ext_vector_type(4))) unsigned short us4;

#define SEQ 2048
#define DMODEL 1024
#define NHEAD 16
#define HEADD 64
#define NBH 32          // B * NHEAD = 2 * 16
#define LUTW 4096       // padded 4095 rel positions

__device__ __forceinline__ unsigned short f2bf(float f) {
    unsigned int u = __builtin_bit_cast(unsigned int, f);
    u = (u + 0x7fffu + ((u >> 16) & 1u)) >> 16;
    return (unsigned short)u;
}
__device__ __forceinline__ float bf2f(unsigned short h) {
    return __builtin_bit_cast(float, (unsigned int)h << 16);
}
__device__ __forceinline__ void split2(float x, unsigned short& h, unsigned short& l) {
    h = f2bf(x);
    l = f2bf(x - bf2f(h));
}

// ---------------- cast fp32 -> bf16, 8 elems/thread ----------------
__global__ __launch_bounds__(256) void cast_kernel(const float* __restrict__ in,
                                                   unsigned short* __restrict__ out, int n) {
    int i = (blockIdx.x * 256 + threadIdx.x) * 8;
    if (i >= n) return;
    f32x4 a = *(const f32x4*)(in + i);
    f32x4 b = *(const f32x4*)(in + i + 4);
    short8 r;
    r[0] = (short)f2bf(a[0]); r[1] = (short)f2bf(a[1]);
    r[2] = (short)f2bf(a[2]); r[3] = (short)f2bf(a[3]);
    r[4] = (short)f2bf(b[0]); r[5] = (short)f2bf(b[1]);
    r[6] = (short)f2bf(b[2]); r[7] = (short)f2bf(b[3]);
    *(short8*)(out + i) = r;
}

// ---------------- split cast fp32 -> bf16 hi + lo ----------------
__global__ __launch_bounds__(256) void split_cast_kernel(const float* __restrict__ in,
                                                         unsigned short* __restrict__ hi,
                                                         unsigned short* __restrict__ lo, int n) {
    int i = (blockIdx.x * 256 + threadIdx.x) * 8;
    if (i >= n) return;
    f32x4 a = *(const f32x4*)(in + i);
    f32x4 b = *(const f32x4*)(in + i + 4);
    short8 rh, rl;
    unsigned short h, l;
#pragma unroll
    for (int j = 0; j < 4; j++) {
        split2(a[j], h, l); rh[j] = (short)h; rl[j] = (short)l;
        split2(b[j], h, l); rh[4 + j] = (short)h; rl[4 + j] = (short)l;
    }
    *(short8*)(hi + i) = rh;
    *(short8*)(lo + i) = rl;
}

// ---------------- T5 relative position bucket -> bias LUT ----------------
__device__ __forceinline__ int rel_bucket(int rel) {
    int ret = (rel > 0) ? 16 : 0;
    int rp = rel < 0 ? -rel : rel;
    if (rp < 8) return ret + rp;
    float x = logf((float)rp * 0.125f) / 2.7725887f * 8.0f;
    int v = 8 + (int)x;
    v = v < 15 ? v : 15;
    return ret + v;
}

__global__ __launch_bounds__(256) void biaslut_kernel(const float* __restrict__ rel_bias,
                                                      float* __restrict__ lut) {
    int i = blockIdx.x * 256 + threadIdx.x;   // 16 * 4096
    if (i >= NHEAD * LUTW) return;
    int h = i >> 12;
    int idx = i & (LUTW - 1);
    int rel = idx - 2047;
    int b = rel_bucket(rel);
    lut[i] = rel_bias[b * NHEAD + h];
}

// ---------------- position_bias output: [1,16,2048,2048] ----------------
__global__ __launch_bounds__(256) void posbias_kernel(const float* __restrict__ lut,
                                                      float* __restrict__ out) {
    size_t idx = (size_t)blockIdx.x * 256 + threadIdx.x;  // one float4 each
    size_t e = idx * 4;
    int k = (int)(e & 2047);
    int q = (int)((e >> 11) & 2047);
    int h = (int)(e >> 22);
    const float* lp = lut + h * LUTW + (k - q + 2047);
    float4 v;
    v.x = lp[0]; v.y = lp[1]; v.z = lp[2]; v.w = lp[3];
    ((float4*)out)[idx] = v;
}

// ---------------- plain bf16 GEMM  C[M,N] = A[M,K] * B[N,K]^T ----------------
// mode 1: C = V transposed -> Vt[bh][hd][s] bf16 ; mode 2: C fp32 row-major
__global__ __launch_bounds__(256) void gemm_bt_kernel(const unsigned short* __restrict__ A,
                                                      const unsigned short* __restrict__ B,
                                                      void* __restrict__ Cout,
                                                      int M, int N, int K, int mode) {
    int l = threadIdx.x & 63, w = threadIdx.x >> 6;
    int row0 = blockIdx.y * 128 + (w >> 1) * 64;
    int col0 = blockIdx.x * 128 + (w & 1) * 64;
    int ar = l & 15, ak = (l >> 4) * 8;
    f32x4 acc[4][4] = {};
    for (int k0 = 0; k0 < K; k0 += 32) {
        short8 af[4], bf[4];
#pragma unroll
        for (int mi = 0; mi < 4; mi++)
            af[mi] = *(const short8*)(A + (size_t)(row0 + mi * 16 + ar) * K + k0 + ak);
#pragma unroll
        for (int ni = 0; ni < 4; ni++)
            bf[ni] = *(const short8*)(B + (size_t)(col0 + ni * 16 + ar) * K + k0 + ak);
#pragma unroll
        for (int mi = 0; mi < 4; mi++)
#pragma unroll
            for (int ni = 0; ni < 4; ni++)
                acc[mi][ni] = __builtin_amdgcn_mfma_f32_16x16x32_bf16(af[mi], bf[ni], acc[mi][ni], 0, 0, 0);
    }
    int cr = (l >> 4) * 4, cc = l & 15;
    if (mode == 1) {
        unsigned short* Vt = (unsigned short*)Cout;
#pragma unroll
        for (int mi = 0; mi < 4; mi++)
#pragma unroll
            for (int ni = 0; ni < 4; ni++) {
                int c = col0 + ni * 16 + cc;
                int h = c >> 6, hd = c & 63;
                int r = row0 + mi * 16 + cr;
                int b = r >> 11, s0 = r & 2047;
                us4 pk;
#pragma unroll
                for (int j = 0; j < 4; j++) pk[j] = f2bf(acc[mi][ni][j]);
                *(us4*)(Vt + (size_t)((b * NHEAD + h) * HEADD + hd) * SEQ + s0) = pk;
            }
    } else {
        float* C = (float*)Cout;
#pragma unroll
        for (int mi = 0; mi < 4; mi++)
#pragma unroll
            for (int ni = 0; ni < 4; ni++) {
                int c = col0 + ni * 16 + cc;
#pragma unroll
                for (int j = 0; j < 4; j++)
                    C[(size_t)(row0 + mi * 16 + cr + j) * N + c] = acc[mi][ni][j];
            }
    }
}

// ---------------- split (emulated-fp32) GEMM: C=(Ah+Al)(Bh+Bl)^T, C stored hi/lo ----------------
__global__ __launch_bounds__(256) void gemm_split_kernel(const unsigned short* __restrict__ Ah,
                                                         const unsigned short* __restrict__ Al,
                                                         const unsigned short* __restrict__ Bh,
                                                         const unsigned short* __restrict__ Bl,
                                                         unsigned short* __restrict__ Ch,
                                                         unsigned short* __restrict__ Cl,
                                                         int M, int N, int K) {
    int l = threadIdx.x & 63, w = threadIdx.x >> 6;
    int row0 = blockIdx.y * 128 + (w >> 1) * 64;
    int col0 = blockIdx.x * 128 + (w & 1) * 64;
    int ar = l & 15, ak = (l >> 4) * 8;
    f32x4 acc[4][4] = {};
    for (int k0 = 0; k0 < K; k0 += 32) {
        short8 ah[4], al[4], bh[4], bl[4];
#pragma unroll
        for (int mi = 0; mi < 4; mi++) {
            size_t o = (size_t)(row0 + mi * 16 + ar) * K + k0 + ak;
            ah[mi] = *(const short8*)(Ah + o);
            al[mi] = *(const short8*)(Al + o);
        }
#pragma unroll
        for (int ni = 0; ni < 4; ni++) {
            size_t o = (size_t)(col0 + ni * 16 + ar) * K + k0 + ak;
            bh[ni] = *(const short8*)(Bh + o);
            bl[ni] = *(const short8*)(Bl + o);
        }
#pragma unroll
        for (int mi = 0; mi < 4; mi++)
#pragma unroll
            for (int ni = 0; ni < 4; ni++) {
                acc[mi][ni] = __builtin_amdgcn_mfma_f32_16x16x32_bf16(ah[mi], bh[ni], acc[mi][ni], 0, 0, 0);
                acc[mi][ni] = __builtin_amdgcn_mfma_f32_16x16x32_bf16(ah[mi], bl[ni], acc[mi][ni], 0, 0, 0);
                acc[mi][ni] = __builtin_amdgcn_mfma_f32_16x16x32_bf16(al[mi], bh[ni], acc[mi][ni], 0, 0, 0);
            }
    }
    int cr = (l >> 4) * 4, cc = l & 15;
#pragma unroll
    for (int mi = 0; mi < 4; mi++)
#pragma unroll
        for (int ni = 0; ni < 4; ni++) {
            int c = col0 + ni * 16 + cc;
#pragma unroll
            for (int j = 0; j < 4; j++) {
                size_t o = (size_t)(row0 + mi * 16 + cr + j) * N + c;
                unsigned short h, lo2;
                split2(acc[mi][ni][j], h, lo2);
                Ch[o] = h; Cl[o] = lo2;
            }
        }
}

// ---------------- scores = Q K^T (split, ~fp32) + bias, mask -> raw scores fp32 ----------------
__global__ __launch_bounds__(256) void scores_split_kernel(const unsigned short* __restrict__ Qh,
                                                           const unsigned short* __restrict__ Ql,
                                                           const unsigned short* __restrict__ Kh,
                                                           const unsigned short* __restrict__ Kl,
                                                           const float* __restrict__ lut,
                                                           const int* __restrict__ mask,
                                                           float* __restrict__ out) {
    int l = threadIdx.x & 63, w = threadIdx.x >> 6;
    int bh = blockIdx.z;
    int b = bh >> 4, h = bh & 15;
    int q0 = blockIdx.y * 128 + (w >> 1) * 64;
    int c0 = blockIdx.x * 128 + (w & 1) * 64;
    size_t hoff = (size_t)(b * SEQ) * DMODEL + h * HEADD;
    int ar = l & 15, ak = (l >> 4) * 8;
    f32x4 acc[4][4] = {};
#pragma unroll
    for (int kk = 0; kk < 64; kk += 32) {
        short8 qh[4], ql[4], kh[4], kl[4];
#pragma unroll
        for (int mi = 0; mi < 4; mi++) {
            size_t o = hoff + (size_t)(q0 + mi * 16 + ar) * DMODEL + kk + ak;
            qh[mi] = *(const short8*)(Qh + o);
            ql[mi] = *(const short8*)(Ql + o);
        }
#pragma unroll
        for (int ni = 0; ni < 4; ni++) {
            size_t o = hoff + (size_t)(c0 + ni * 16 + ar) * DMODEL + kk + ak;
            kh[ni] = *(const short8*)(Kh + o);
            kl[ni] = *(const short8*)(Kl + o);
        }
#pragma unroll
        for (int mi = 0; mi < 4; mi++)
#pragma unroll
            for (int ni = 0; ni < 4; ni++) {
                acc[mi][ni] = __builtin_amdgcn_mfma_f32_16x16x32_bf16(qh[mi], kh[ni], acc[mi][ni], 0, 0, 0);
                acc[mi][ni] = __builtin_amdgcn_mfma_f32_16x16x32_bf16(qh[mi], kl[ni], acc[mi][ni], 0, 0, 0);
                acc[mi][ni] = __builtin_amdgcn_mfma_f32_16x16x32_bf16(ql[mi], kh[ni], acc[mi][ni], 0, 0, 0);
            }
    }
    const float* luth = lut + h * LUTW;
    float* ob = out + (size_t)bh * SEQ * SEQ;
    int cr = (l >> 4) * 4, cc = l & 15;
#pragma unroll
    for (int ni = 0; ni < 4; ni++) {
        int c = c0 + ni * 16 + cc;
        int mv = mask[b * SEQ + c];
#pragma unroll
        for (int mi = 0; mi < 4; mi++) {
            int r = q0 + mi * 16 + cr;
#pragma unroll
            for (int j = 0; j < 4; j++) {
                float v = mv ? (acc[mi][ni][j] + luth[c - (r + j) + 2047]) : -1e9f;
                ob[(size_t)(r + j) * SEQ + c] = v;
            }
        }
    }
}

// ---------------- row softmax in place, one block per row ----------------
__global__ __launch_bounds__(256) void softmax_kernel(float* __restrict__ wts) {
    size_t row = blockIdx.x;
    float* p = wts + row * SEQ;
    int t = threadIdx.x, l = t & 63, w = t >> 6;
    float4 v0 = ((float4*)p)[t];
    float4 v1 = ((float4*)p)[t + 256];
    float mx = fmaxf(fmaxf(fmaxf(v0.x, v0.y), fmaxf(v0.z, v0.w)),
                     fmaxf(fmaxf(v1.x, v1.y), fmaxf(v1.z, v1.w)));
    for (int off = 32; off; off >>= 1) mx = fmaxf(mx, __shfl_xor(mx, off));
    __shared__ float red[8];
    if (l == 0) red[w] = mx;
    __syncthreads();
    mx = fmaxf(fmaxf(red[0], red[1]), fmaxf(red[2], red[3]));
    v0.x = expf(v0.x - mx); v0.y = expf(v0.y - mx);
    v0.z = expf(v0.z - mx); v0.w = expf(v0.w - mx);
    v1.x = expf(v1.x - mx); v1.y = expf(v1.y - mx);
    v1.z = expf(v1.z - mx); v1.w = expf(v1.w - mx);
    float s = v0.x + v0.y + v0.z + v0.w + v1.x + v1.y + v1.z + v1.w;
    for (int off = 32; off; off >>= 1) s += __shfl_xor(s, off);
    if (l == 0) red[4 + w] = s;
    __syncthreads();
    s = (red[4] + red[5]) + (red[6] + red[7]);
    float inv = 1.0f / s;
    v0.x *= inv; v0.y *= inv; v0.z *= inv; v0.w *= inv;
    v1.x *= inv; v1.y *= inv; v1.z *= inv; v1.w *= inv;
    ((float4*)p)[t] = v0;
    ((float4*)p)[t + 256] = v1;
}

// ---------------- PV: attn0[b,q,h*64+hd] = sum_k W[bh,q,k] * Vt[bh,hd,k] ----------------
__global__ __launch_bounds__(256) void pv_kernel(const float* __restrict__ Wt,
                                                 const unsigned short* __restrict__ Vt,
                                                 unsigned short* __restrict__ attn0) {
    int l = threadIdx.x & 63, w = threadIdx.x >> 6;
    int bh = blockIdx.y;
    int b = bh >> 4, h = bh & 15;
    int m0 = blockIdx.x * 64 + w * 16;
    const float* Wb = Wt + (size_t)bh * SEQ * SEQ;
    const unsigned short* Vb = Vt + (size_t)bh * HEADD * SEQ;
    int ar = l & 15, ak = (l >> 4) * 8;
    f32x4 acc[4] = {};
    for (int k0 = 0; k0 < SEQ; k0 += 32) {
        const float* ap = Wb + (size_t)(m0 + ar) * SEQ + k0 + ak;
        f32x4 a0 = *(const f32x4*)ap;
        f32x4 a1 = *(const f32x4*)(ap + 4);
        short8 af;
        af[0] = (short)f2bf(a0[0]); af[1] = (short)f2bf(a0[1]);
        af[2] = (short)f2bf(a0[2]); af[3] = (short)f2bf(a0[3]);
        af[4] = (short)f2bf(a1[0]); af[5] = (short)f2bf(a1[1]);
        af[6] = (short)f2bf(a1[2]); af[7] = (short)f2bf(a1[3]);
#pragma unroll
        for (int ni = 0; ni < 4; ni++) {
            short8 bf = *(const short8*)(Vb + (size_t)(ni * 16 + ar) * SEQ + k0 + ak);
            acc[ni] = __builtin_amdgcn_mfma_f32_16x16x32_bf16(af, bf, acc[ni], 0, 0, 0);
        }
    }
    int cr = (l >> 4) * 4, cc = l & 15;
#pragma unroll
    for (int ni = 0; ni < 4; ni++)
#pragma unroll
        for (int j = 0; j < 4; j++)
            attn0[(size_t)(b * SEQ + m0 + cr + j) * DMODEL + h * HEADD + ni * 16 + cc] =
                f2bf(acc[ni][j]);
}

extern "C" void kernel_launch(void* const* d_in, const int* in_sizes, int n_in,
                              void* d_out, int out_size, void* d_ws, size_t ws_size,
                              hipStream_t stream) {
    const float* hs = (const float*)d_in[0];
    const int* mask = (const int*)d_in[1];
    const float* Wq = (const float*)d_in[2];
    const float* Wk = (const float*)d_in[3];
    const float* Wv = (const float*)d_in[4];
    const float* Wo = (const float*)d_in[5];
    const float* rel_bias = (const float*)d_in[6];

    float* out_attn = (float*)d_out;                       // [2,2048,1024]
    float* out_wts = out_attn + (size_t)2 * SEQ * DMODEL;  // [2,16,2048,2048]
    float* out_posb = out_wts + (size_t)NBH * SEQ * SEQ;   // [1,16,2048,2048]

    char* ws = (char*)d_ws;
    size_t off = 0;
    auto carve = [&](size_t bytes) { void* p = ws + off; off += (bytes + 255) & ~(size_t)255; return p; };
    unsigned short* Xh  = (unsigned short*)carve((size_t)2 * SEQ * DMODEL * 2);
    unsigned short* Xl  = (unsigned short*)carve((size_t)2 * SEQ * DMODEL * 2);
    unsigned short* Wqh = (unsigned short*)carve((size_t)DMODEL * DMODEL * 2);
    unsigned short* Wql = (unsigned short*)carve((size_t)DMODEL * DMODEL * 2);
    unsigned short* Wkh = (unsigned short*)carve((size_t)DMODEL * DMODEL * 2);
    unsigned short* Wkl = (unsigned short*)carve((size_t)DMODEL * DMODEL * 2);
    unsigned short* Wvb = (unsigned short*)carve((size_t)DMODEL * DMODEL * 2);
    unsigned short* Wob = (unsigned short*)carve((size_t)DMODEL * DMODEL * 2);
    unsigned short* Qh  = (unsigned short*)carve((size_t)2 * SEQ * DMODEL * 2);
    unsigned short* Ql  = (unsigned short*)carve((size_t)2 * SEQ * DMODEL * 2);
    unsigned short* Kh  = (unsigned short*)carve((size_t)2 * SEQ * DMODEL * 2);
    unsigned short* Kl  = (unsigned short*)carve((size_t)2 * SEQ * DMODEL * 2);
    unsigned short* Vt  = (unsigned short*)carve((size_t)NBH * HEADD * SEQ * 2);
    unsigned short* A0b = (unsigned short*)carve((size_t)2 * SEQ * DMODEL * 2);
    float* lut          = (float*)carve((size_t)NHEAD * LUTW * 4);

    int nX = 2 * SEQ * DMODEL;   // 4194304
    int nW = DMODEL * DMODEL;    // 1048576

    split_cast_kernel<<<nX / 8 / 256, 256, 0, stream>>>(hs, Xh, Xl, nX);
    split_cast_kernel<<<nW / 8 / 256, 256, 0, stream>>>(Wq, Wqh, Wql, nW);
    split_cast_kernel<<<nW / 8 / 256, 256, 0, stream>>>(Wk, Wkh, Wkl, nW);
    cast_kernel<<<nW / 8 / 256, 256, 0, stream>>>(Wv, Wvb, nW);
    cast_kernel<<<nW / 8 / 256, 256, 0, stream>>>(Wo, Wob, nW);
    biaslut_kernel<<<NHEAD * LUTW / 256, 256, 0, stream>>>(rel_bias, lut);

    // projections: M=4096, N=1024, K=1024
    dim3 pg(DMODEL / 128, (2 * SEQ) / 128);
    gemm_split_kernel<<<pg, 256, 0, stream>>>(Xh, Xl, Wqh, Wql, Qh, Ql, 2 * SEQ, DMODEL, DMODEL);
    gemm_split_kernel<<<pg, 256, 0, stream>>>(Xh, Xl, Wkh, Wkl, Kh, Kl, 2 * SEQ, DMODEL, DMODEL);
    gemm_bt_kernel<<<pg, 256, 0, stream>>>(Xh, Wvb, Vt, 2 * SEQ, DMODEL, DMODEL, 1);

    // position bias output
    posbias_kernel<<<(NHEAD * SEQ * SEQ / 4) / 256, 256, 0, stream>>>(lut, out_posb);

    // raw scores into attn_weights slot (emulated fp32)
    dim3 sg(SEQ / 128, SEQ / 128, NBH);
    scores_split_kernel<<<sg, 256, 0, stream>>>(Qh, Ql, Kh, Kl, lut, mask, out_wts);

    // softmax in place, one block per row
    softmax_kernel<<<NBH * SEQ, 256, 0, stream>>>(out_wts);

    // PV
    dim3 vg(SEQ / 64, NBH);
    pv_kernel<<<vg, 256, 0, stream>>>(out_wts, Vt, A0b);

    // final projection -> out_attn (fp32)
    gemm_bt_kernel<<<pg, 256, 0, stream>>>(A0b, Wob, out_attn, 2 * SEQ, DMODEL, DMODEL, 2);
}

// Round 3
// 847.421 us; speedup vs baseline: 1.2489x; 1.2489x over previous
//
#include <hip/hip_runtime.h>

typedef __attribute__((ext_vector_type(8))) _Float16 half8;
typedef __attribute__((ext_vector_type(4))) _Float16 half4;
typedef __attribute__((ext_vector_type(4))) float f32x4;

#define SEQ 2048
#define DMODEL 1024
#define NHEAD 16
#define HEADD 64
#define NBH 32          // B * NHEAD
#define LUTW 4096

// ---------------- cast fp32 -> fp16, 8 elems/thread ----------------
__global__ __launch_bounds__(256) void cast_h_kernel(const float* __restrict__ in,
                                                     _Float16* __restrict__ out, int n) {
    int i = (blockIdx.x * 256 + threadIdx.x) * 8;
    if (i >= n) return;
    f32x4 a = *(const f32x4*)(in + i);
    f32x4 b = *(const f32x4*)(in + i + 4);
    half8 r;
    r[0] = (_Float16)a[0]; r[1] = (_Float16)a[1];
    r[2] = (_Float16)a[2]; r[3] = (_Float16)a[3];
    r[4] = (_Float16)b[0]; r[5] = (_Float16)b[1];
    r[6] = (_Float16)b[2]; r[7] = (_Float16)b[3];
    *(half8*)(out + i) = r;
}

// ---------------- T5 relative position bucket -> bias LUT ----------------
__device__ __forceinline__ int rel_bucket(int rel) {
    int ret = (rel > 0) ? 16 : 0;
    int rp = rel < 0 ? -rel : rel;
    if (rp < 8) return ret + rp;
    float x = logf((float)rp * 0.125f) / 2.7725887f * 8.0f;
    int v = 8 + (int)x;
    v = v < 15 ? v : 15;
    return ret + v;
}

__global__ __launch_bounds__(256) void biaslut_kernel(const float* __restrict__ rel_bias,
                                                      float* __restrict__ lut) {
    int i = blockIdx.x * 256 + threadIdx.x;   // 16 * 4096
    if (i >= NHEAD * LUTW) return;
    int h = i >> 12;
    int idx = i & (LUTW - 1);
    int rel = idx - 2047;
    int b = rel_bucket(rel);
    lut[i] = rel_bias[b * NHEAD + h];
}

// ---------------- position_bias output: [1,16,2048,2048] ----------------
__global__ __launch_bounds__(256) void posbias_kernel(const float* __restrict__ lut,
                                                      float* __restrict__ out) {
    size_t idx = (size_t)blockIdx.x * 256 + threadIdx.x;  // one float4 each
    size_t e = idx * 4;
    int k = (int)(e & 2047);
    int q = (int)((e >> 11) & 2047);
    int h = (int)(e >> 22);
    const float* lp = lut + h * LUTW + (k - q + 2047);
    float4 v;
    v.x = lp[0]; v.y = lp[1]; v.z = lp[2]; v.w = lp[3];
    ((float4*)out)[idx] = v;
}

// ---------------- fp16 GEMM  C[M,N] = A[M,K] * B[N,K]^T ----------------
// mode 0: C fp16 row-major ; mode 1: C = V transposed -> Vt[bh][hd][s] fp16
// mode 2: C fp32 row-major
__global__ __launch_bounds__(256) void gemm_bt_h_kernel(const _Float16* __restrict__ A,
                                                        const _Float16* __restrict__ B,
                                                        void* __restrict__ Cout,
                                                        int M, int N, int K, int mode) {
    int l = threadIdx.x & 63, w = threadIdx.x >> 6;
    int row0 = blockIdx.y * 128 + (w >> 1) * 64;
    int col0 = blockIdx.x * 128 + (w & 1) * 64;
    int ar = l & 15, ak = (l >> 4) * 8;
    f32x4 acc[4][4] = {};
    for (int k0 = 0; k0 < K; k0 += 32) {
        half8 af[4], bf[4];
#pragma unroll
        for (int mi = 0; mi < 4; mi++)
            af[mi] = *(const half8*)(A + (size_t)(row0 + mi * 16 + ar) * K + k0 + ak);
#pragma unroll
        for (int ni = 0; ni < 4; ni++)
            bf[ni] = *(const half8*)(B + (size_t)(col0 + ni * 16 + ar) * K + k0 + ak);
#pragma unroll
        for (int mi = 0; mi < 4; mi++)
#pragma unroll
            for (int ni = 0; ni < 4; ni++)
                acc[mi][ni] = __builtin_amdgcn_mfma_f32_16x16x32_f16(af[mi], bf[ni], acc[mi][ni], 0, 0, 0);
    }
    int cr = (l >> 4) * 4, cc = l & 15;
    if (mode == 0) {
        _Float16* C = (_Float16*)Cout;
#pragma unroll
        for (int mi = 0; mi < 4; mi++)
#pragma unroll
            for (int ni = 0; ni < 4; ni++) {
                int c = col0 + ni * 16 + cc;
#pragma unroll
                for (int j = 0; j < 4; j++)
                    C[(size_t)(row0 + mi * 16 + cr + j) * N + c] = (_Float16)acc[mi][ni][j];
            }
    } else if (mode == 1) {
        _Float16* Vt = (_Float16*)Cout;
#pragma unroll
        for (int mi = 0; mi < 4; mi++)
#pragma unroll
            for (int ni = 0; ni < 4; ni++) {
                int c = col0 + ni * 16 + cc;
                int h = c >> 6, hd = c & 63;
                int r = row0 + mi * 16 + cr;
                int b = r >> 11, s0 = r & 2047;
                half4 pk;
#pragma unroll
                for (int j = 0; j < 4; j++) pk[j] = (_Float16)acc[mi][ni][j];
                *(half4*)(Vt + (size_t)((b * NHEAD + h) * HEADD + hd) * SEQ + s0) = pk;
            }
    } else {
        float* C = (float*)Cout;
#pragma unroll
        for (int mi = 0; mi < 4; mi++)
#pragma unroll
            for (int ni = 0; ni < 4; ni++) {
                int c = col0 + ni * 16 + cc;
#pragma unroll
                for (int j = 0; j < 4; j++)
                    C[(size_t)(row0 + mi * 16 + cr + j) * N + c] = acc[mi][ni][j];
            }
    }
}

// ---------------- scores = Q K^T + bias, mask -> raw fp32 + per-tile softmax partials ----------------
__global__ __launch_bounds__(256) void scores_stats_kernel(const _Float16* __restrict__ Q,
                                                           const _Float16* __restrict__ Kmat,
                                                           const float* __restrict__ lut,
                                                           const int* __restrict__ mask,
                                                           float* __restrict__ out,
                                                           float2* __restrict__ partials) {
    int l = threadIdx.x & 63, w = threadIdx.x >> 6;
    int bh = blockIdx.z;
    int b = bh >> 4, h = bh & 15;
    int q0 = blockIdx.y * 128 + (w >> 1) * 64;
    int c0 = blockIdx.x * 128 + (w & 1) * 64;
    int tilecol = blockIdx.x * 2 + (w & 1);
    size_t hoff = (size_t)(b * SEQ) * DMODEL + h * HEADD;
    int ar = l & 15, ak = (l >> 4) * 8;
    f32x4 acc[4][4] = {};
#pragma unroll
    for (int kk = 0; kk < 64; kk += 32) {
        half8 qf[4], kf[4];
#pragma unroll
        for (int mi = 0; mi < 4; mi++)
            qf[mi] = *(const half8*)(Q + hoff + (size_t)(q0 + mi * 16 + ar) * DMODEL + kk + ak);
#pragma unroll
        for (int ni = 0; ni < 4; ni++)
            kf[ni] = *(const half8*)(Kmat + hoff + (size_t)(c0 + ni * 16 + ar) * DMODEL + kk + ak);
#pragma unroll
        for (int mi = 0; mi < 4; mi++)
#pragma unroll
            for (int ni = 0; ni < 4; ni++)
                acc[mi][ni] = __builtin_amdgcn_mfma_f32_16x16x32_f16(qf[mi], kf[ni], acc[mi][ni], 0, 0, 0);
    }
    const float* luth = lut + h * LUTW;
    float* ob = out + (size_t)bh * SEQ * SEQ;
    int cr = (l >> 4) * 4, cc = l & 15;
    int mv[4];
#pragma unroll
    for (int ni = 0; ni < 4; ni++) mv[ni] = mask[b * SEQ + c0 + ni * 16 + cc];
#pragma unroll
    for (int mi = 0; mi < 4; mi++) {
#pragma unroll
        for (int j = 0; j < 4; j++) {
            int r = q0 + mi * 16 + cr + j;
            float vv[4];
#pragma unroll
            for (int ni = 0; ni < 4; ni++) {
                int c = c0 + ni * 16 + cc;
                float v = mv[ni] ? (acc[mi][ni][j] + luth[c - r + 2047]) : -1e9f;
                ob[(size_t)r * SEQ + c] = v;
                vv[ni] = v;
            }
            // per-row (16 lanes share a row) tile max + sumexp
            float mt = fmaxf(fmaxf(vv[0], vv[1]), fmaxf(vv[2], vv[3]));
            mt = fmaxf(mt, __shfl_xor(mt, 1));
            mt = fmaxf(mt, __shfl_xor(mt, 2));
            mt = fmaxf(mt, __shfl_xor(mt, 4));
            mt = fmaxf(mt, __shfl_xor(mt, 8));
            float le = __expf(vv[0] - mt) + __expf(vv[1] - mt) +
                       __expf(vv[2] - mt) + __expf(vv[3] - mt);
            le += __shfl_xor(le, 1);
            le += __shfl_xor(le, 2);
            le += __shfl_xor(le, 4);
            le += __shfl_xor(le, 8);
            if ((l & 15) == 0)
                partials[(size_t)(bh * SEQ + r) * 32 + tilecol] = make_float2(mt, le);
        }
    }
}

// ---------------- reduce partials -> per-row (max, 1/sum) ----------------
__global__ __launch_bounds__(256) void reduce_stats_kernel(const float2* __restrict__ partials,
                                                           float2* __restrict__ stats) {
    int row = blockIdx.x * 256 + threadIdx.x;   // NBH*SEQ rows
    const float2* p = partials + (size_t)row * 32;
    float m = -3e38f;
#pragma unroll
    for (int i = 0; i < 32; i++) m = fmaxf(m, p[i].x);
    float lsum = 0.f;
#pragma unroll
    for (int i = 0; i < 32; i++) lsum += p[i].y * __expf(p[i].x - m);
    stats[row] = make_float2(m, 1.0f / lsum);
}

// ---------------- fused: normalize -> weights (in place) + PV -> attn0 fp16 ----------------
__global__ __launch_bounds__(256) void pv_fused_kernel(float* __restrict__ wts,
                                                       const _Float16* __restrict__ Vt,
                                                       const float2* __restrict__ stats,
                                                       _Float16* __restrict__ attn0) {
    int l = threadIdx.x & 63, w = threadIdx.x >> 6;
    int bh = blockIdx.y;
    int b = bh >> 4, h = bh & 15;
    int m0 = blockIdx.x * 64 + w * 16;
    float* Wb = wts + (size_t)bh * SEQ * SEQ;
    const _Float16* Vb = Vt + (size_t)bh * HEADD * SEQ;
    int ar = l & 15, ak = (l >> 4) * 8;
    float2 st = stats[bh * SEQ + m0 + ar];
    float m = st.x, invl = st.y;
    f32x4 acc[4] = {};
    for (int k0 = 0; k0 < SEQ; k0 += 32) {
        float* ap = Wb + (size_t)(m0 + ar) * SEQ + k0 + ak;
        f32x4 a0 = *(const f32x4*)ap;
        f32x4 a1 = *(const f32x4*)(ap + 4);
        half8 af;
        f32x4 w0, w1;
#pragma unroll
        for (int j = 0; j < 4; j++) {
            w0[j] = __expf(a0[j] - m) * invl;
            w1[j] = __expf(a1[j] - m) * invl;
            af[j] = (_Float16)w0[j];
            af[4 + j] = (_Float16)w1[j];
        }
        *(f32x4*)ap = w0;
        *(f32x4*)(ap + 4) = w1;
#pragma unroll
        for (int ni = 0; ni < 4; ni++) {
            half8 bf = *(const half8*)(Vb + (size_t)(ni * 16 + ar) * SEQ + k0 + ak);
            acc[ni] = __builtin_amdgcn_mfma_f32_16x16x32_f16(af, bf, acc[ni], 0, 0, 0);
        }
    }
    int cr = (l >> 4) * 4, cc = l & 15;
#pragma unroll
    for (int ni = 0; ni < 4; ni++)
#pragma unroll
        for (int j = 0; j < 4; j++)
            attn0[(size_t)(b * SEQ + m0 + cr + j) * DMODEL + h * HEADD + ni * 16 + cc] =
                (_Float16)acc[ni][j];
}

extern "C" void kernel_launch(void* const* d_in, const int* in_sizes, int n_in,
                              void* d_out, int out_size, void* d_ws, size_t ws_size,
                              hipStream_t stream) {
    const float* hs = (const float*)d_in[0];
    const int* mask = (const int*)d_in[1];
    const float* Wq = (const float*)d_in[2];
    const float* Wk = (const float*)d_in[3];
    const float* Wv = (const float*)d_in[4];
    const float* Wo = (const float*)d_in[5];
    const float* rel_bias = (const float*)d_in[6];

    float* out_attn = (float*)d_out;                       // [2,2048,1024]
    float* out_wts = out_attn + (size_t)2 * SEQ * DMODEL;  // [2,16,2048,2048]
    float* out_posb = out_wts + (size_t)NBH * SEQ * SEQ;   // [1,16,2048,2048]

    char* ws = (char*)d_ws;
    size_t off = 0;
    auto carve = [&](size_t bytes) { void* p = ws + off; off += (bytes + 255) & ~(size_t)255; return p; };
    _Float16* Xh  = (_Float16*)carve((size_t)2 * SEQ * DMODEL * 2);
    _Float16* Wqh = (_Float16*)carve((size_t)DMODEL * DMODEL * 2);
    _Float16* Wkh = (_Float16*)carve((size_t)DMODEL * DMODEL * 2);
    _Float16* Wvh = (_Float16*)carve((size_t)DMODEL * DMODEL * 2);
    _Float16* Woh = (_Float16*)carve((size_t)DMODEL * DMODEL * 2);
    _Float16* Qh  = (_Float16*)carve((size_t)2 * SEQ * DMODEL * 2);
    _Float16* Kh  = (_Float16*)carve((size_t)2 * SEQ * DMODEL * 2);
    _Float16* Vt  = (_Float16*)carve((size_t)NBH * HEADD * SEQ * 2);
    _Float16* A0h = (_Float16*)carve((size_t)2 * SEQ * DMODEL * 2);
    float* lut    = (float*)carve((size_t)NHEAD * LUTW * 4);
    float2* partials = (float2*)carve((size_t)NBH * SEQ * 32 * 8);
    float2* stats    = (float2*)carve((size_t)NBH * SEQ * 8);

    int nX = 2 * SEQ * DMODEL;   // 4194304
    int nW = DMODEL * DMODEL;    // 1048576

    cast_h_kernel<<<nX / 8 / 256, 256, 0, stream>>>(hs, Xh, nX);
    cast_h_kernel<<<nW / 8 / 256, 256, 0, stream>>>(Wq, Wqh, nW);
    cast_h_kernel<<<nW / 8 / 256, 256, 0, stream>>>(Wk, Wkh, nW);
    cast_h_kernel<<<nW / 8 / 256, 256, 0, stream>>>(Wv, Wvh, nW);
    cast_h_kernel<<<nW / 8 / 256, 256, 0, stream>>>(Wo, Woh, nW);
    biaslut_kernel<<<NHEAD * LUTW / 256, 256, 0, stream>>>(rel_bias, lut);

    // projections: M=4096, N=1024, K=1024
    dim3 pg(DMODEL / 128, (2 * SEQ) / 128);
    gemm_bt_h_kernel<<<pg, 256, 0, stream>>>(Xh, Wqh, Qh, 2 * SEQ, DMODEL, DMODEL, 0);
    gemm_bt_h_kernel<<<pg, 256, 0, stream>>>(Xh, Wkh, Kh, 2 * SEQ, DMODEL, DMODEL, 0);
    gemm_bt_h_kernel<<<pg, 256, 0, stream>>>(Xh, Wvh, Vt, 2 * SEQ, DMODEL, DMODEL, 1);

    // position bias output
    posbias_kernel<<<(NHEAD * SEQ * SEQ / 4) / 256, 256, 0, stream>>>(lut, out_posb);

    // raw scores + softmax partials
    dim3 sg(SEQ / 128, SEQ / 128, NBH);
    scores_stats_kernel<<<sg, 256, 0, stream>>>(Qh, Kh, lut, mask, out_wts, partials);

    // per-row stats
    reduce_stats_kernel<<<NBH * SEQ / 256, 256, 0, stream>>>(partials, stats);

    // fused normalize + weights write + PV
    dim3 vg(SEQ / 64, NBH);
    pv_fused_kernel<<<vg, 256, 0, stream>>>(out_wts, Vt, stats, A0h);

    // final projection -> out_attn (fp32)
    gemm_bt_h_kernel<<<pg, 256, 0, stream>>>(A0h, Woh, out_attn, 2 * SEQ, DMODEL, DMODEL, 2);
}

// Round 4
// 785.290 us; speedup vs baseline: 1.3477x; 1.0791x over previous
//
#include <hip/hip_runtime.h>

typedef __attribute__((ext_vector_type(8))) _Float16 half8;
typedef __attribute__((ext_vector_type(4))) _Float16 half4;
typedef __attribute__((ext_vector_type(4))) float f32x4;

#define SEQ 2048
#define DMODEL 1024
#define NHEAD 16
#define HEADD 64
#define NBH 32          // B * NHEAD
#define LUTW 4096

// ---------------- cast fp32 -> fp16, 8 elems/thread ----------------
__global__ __launch_bounds__(256) void cast_h_kernel(const float* __restrict__ in,
                                                     _Float16* __restrict__ out, int n) {
    int i = (blockIdx.x * 256 + threadIdx.x) * 8;
    if (i >= n) return;
    f32x4 a = *(const f32x4*)(in + i);
    f32x4 b = *(const f32x4*)(in + i + 4);
    half8 r;
    r[0] = (_Float16)a[0]; r[1] = (_Float16)a[1];
    r[2] = (_Float16)a[2]; r[3] = (_Float16)a[3];
    r[4] = (_Float16)b[0]; r[5] = (_Float16)b[1];
    r[6] = (_Float16)b[2]; r[7] = (_Float16)b[3];
    *(half8*)(out + i) = r;
}

// ---------------- T5 relative position bucket -> bias LUT ----------------
__device__ __forceinline__ int rel_bucket(int rel) {
    int ret = (rel > 0) ? 16 : 0;
    int rp = rel < 0 ? -rel : rel;
    if (rp < 8) return ret + rp;
    float x = logf((float)rp * 0.125f) / 2.7725887f * 8.0f;
    int v = 8 + (int)x;
    v = v < 15 ? v : 15;
    return ret + v;
}

__global__ __launch_bounds__(256) void biaslut_kernel(const float* __restrict__ rel_bias,
                                                      float* __restrict__ lut) {
    int i = blockIdx.x * 256 + threadIdx.x;   // 16 * 4096
    if (i >= NHEAD * LUTW) return;
    int h = i >> 12;
    int idx = i & (LUTW - 1);
    int rel = idx - 2047;
    int b = rel_bucket(rel);
    lut[i] = rel_bias[b * NHEAD + h];
}

// ---------------- position_bias output: [1,16,2048,2048] ----------------
__global__ __launch_bounds__(256) void posbias_kernel(const float* __restrict__ lut,
                                                      float* __restrict__ out) {
    size_t idx = (size_t)blockIdx.x * 256 + threadIdx.x;  // one float4 each
    size_t e = idx * 4;
    int k = (int)(e & 2047);
    int q = (int)((e >> 11) & 2047);
    int h = (int)(e >> 22);
    const float* lp = lut + h * LUTW + (k - q + 2047);
    float4 v;
    v.x = lp[0]; v.y = lp[1]; v.z = lp[2]; v.w = lp[3];
    ((float4*)out)[idx] = v;
}

// ---------------- fp16 GEMM  C[M,N] = A[M,K] * B[N,K]^T ----------------
// mode 0: C fp16 row-major ; mode 1: C = V transposed -> Vt[bh][hd][s] fp16
// mode 2: C fp32 row-major
__global__ __launch_bounds__(256) void gemm_bt_h_kernel(const _Float16* __restrict__ A,
                                                        const _Float16* __restrict__ B,
                                                        void* __restrict__ Cout,
                                                        int M, int N, int K, int mode) {
    int l = threadIdx.x & 63, w = threadIdx.x >> 6;
    int row0 = blockIdx.y * 128 + (w >> 1) * 64;
    int col0 = blockIdx.x * 128 + (w & 1) * 64;
    int ar = l & 15, ak = (l >> 4) * 8;
    f32x4 acc[4][4] = {};
    for (int k0 = 0; k0 < K; k0 += 32) {
        half8 af[4], bf[4];
#pragma unroll
        for (int mi = 0; mi < 4; mi++)
            af[mi] = *(const half8*)(A + (size_t)(row0 + mi * 16 + ar) * K + k0 + ak);
#pragma unroll
        for (int ni = 0; ni < 4; ni++)
            bf[ni] = *(const half8*)(B + (size_t)(col0 + ni * 16 + ar) * K + k0 + ak);
#pragma unroll
        for (int mi = 0; mi < 4; mi++)
#pragma unroll
            for (int ni = 0; ni < 4; ni++)
                acc[mi][ni] = __builtin_amdgcn_mfma_f32_16x16x32_f16(af[mi], bf[ni], acc[mi][ni], 0, 0, 0);
    }
    int cr = (l >> 4) * 4, cc = l & 15;
    if (mode == 0) {
        _Float16* C = (_Float16*)Cout;
#pragma unroll
        for (int mi = 0; mi < 4; mi++)
#pragma unroll
            for (int ni = 0; ni < 4; ni++) {
                int c = col0 + ni * 16 + cc;
#pragma unroll
                for (int j = 0; j < 4; j++)
                    C[(size_t)(row0 + mi * 16 + cr + j) * N + c] = (_Float16)acc[mi][ni][j];
            }
    } else if (mode == 1) {
        _Float16* Vt = (_Float16*)Cout;
#pragma unroll
        for (int mi = 0; mi < 4; mi++)
#pragma unroll
            for (int ni = 0; ni < 4; ni++) {
                int c = col0 + ni * 16 + cc;
                int h = c >> 6, hd = c & 63;
                int r = row0 + mi * 16 + cr;
                int b = r >> 11, s0 = r & 2047;
                half4 pk;
#pragma unroll
                for (int j = 0; j < 4; j++) pk[j] = (_Float16)acc[mi][ni][j];
                *(half4*)(Vt + (size_t)((b * NHEAD + h) * HEADD + hd) * SEQ + s0) = pk;
            }
    } else {
        float* C = (float*)Cout;
#pragma unroll
        for (int mi = 0; mi < 4; mi++)
#pragma unroll
            for (int ni = 0; ni < 4; ni++) {
                int c = col0 + ni * 16 + cc;
#pragma unroll
                for (int j = 0; j < 4; j++)
                    C[(size_t)(row0 + mi * 16 + cr + j) * N + c] = acc[mi][ni][j];
            }
    }
}

// ---------------- Pass A: per-row softmax stats via online reduction ----------------
// Swapped-operand S^T = mfma(K,Q): lane holds 16 k-values for ONE q -> per-lane online (m,l).
__global__ __launch_bounds__(256) void stats_kernel(const _Float16* __restrict__ Q,
                                                    const _Float16* __restrict__ Kmat,
                                                    const float* __restrict__ lut,
                                                    const int* __restrict__ mask,
                                                    float2* __restrict__ stats) {
    int l = threadIdx.x & 63, w = threadIdx.x >> 6;
    int bh = blockIdx.y;
    int b = bh >> 4, h = bh & 15;
    int qbase = blockIdx.x * 128 + w * 32;
    size_t hoff = (size_t)(b * SEQ) * DMODEL + h * HEADD;
    int ar = l & 15, g = l >> 4, ak = g * 8;
    const float* luth = lut + h * LUTW;

    half8 qf[2][2];
#pragma unroll
    for (int qi = 0; qi < 2; qi++)
#pragma unroll
        for (int kk = 0; kk < 2; kk++)
            qf[qi][kk] = *(const half8*)(Q + hoff + (size_t)(qbase + qi * 16 + ar) * DMODEL + kk * 32 + ak);

    float m[2] = {-3e38f, -3e38f};
    float lsum[2] = {0.f, 0.f};

    for (int k0 = 0; k0 < SEQ; k0 += 64) {
        half8 kf[4][2];
#pragma unroll
        for (int ni = 0; ni < 4; ni++)
#pragma unroll
            for (int kk = 0; kk < 2; kk++)
                kf[ni][kk] = *(const half8*)(Kmat + hoff + (size_t)(k0 + ni * 16 + ar) * DMODEL + kk * 32 + ak);
        f32x4 acc[4][2] = {};
#pragma unroll
        for (int ni = 0; ni < 4; ni++)
#pragma unroll
            for (int qi = 0; qi < 2; qi++)
#pragma unroll
                for (int kk = 0; kk < 2; kk++)
                    acc[ni][qi] = __builtin_amdgcn_mfma_f32_16x16x32_f16(kf[ni][kk], qf[qi][kk], acc[ni][qi], 0, 0, 0);
        int4 mk[4];
#pragma unroll
        for (int ni = 0; ni < 4; ni++)
            mk[ni] = *(const int4*)(mask + b * SEQ + k0 + ni * 16 + g * 4);
#pragma unroll
        for (int qi = 0; qi < 2; qi++) {
            int q = qbase + qi * 16 + ar;
            float vv[16];
            float vmax = -3e38f;
#pragma unroll
            for (int ni = 0; ni < 4; ni++) {
                const int* mp = (const int*)&mk[ni];
#pragma unroll
                for (int j = 0; j < 4; j++) {
                    int k = k0 + ni * 16 + g * 4 + j;
                    float v = mp[j] ? (acc[ni][qi][j] + luth[k - q + 2047]) : -1e9f;
                    vv[ni * 4 + j] = v;
                    vmax = fmaxf(vmax, v);
                }
            }
            float mn = fmaxf(m[qi], vmax);
            float scale = __expf(m[qi] - mn);
            float s = 0.f;
#pragma unroll
            for (int t = 0; t < 16; t++) s += __expf(vv[t] - mn);
            lsum[qi] = lsum[qi] * scale + s;
            m[qi] = mn;
        }
    }
    // reduce across the 4 lane-groups sharing the same q (xor 16, 32)
#pragma unroll
    for (int qi = 0; qi < 2; qi++) {
#pragma unroll
        for (int off = 16; off <= 32; off <<= 1) {
            float mo = __shfl_xor(m[qi], off);
            float lo = __shfl_xor(lsum[qi], off);
            float mn = fmaxf(m[qi], mo);
            lsum[qi] = lsum[qi] * __expf(m[qi] - mn) + lo * __expf(mo - mn);
            m[qi] = mn;
        }
        if (g == 0)
            stats[bh * SEQ + qbase + qi * 16 + ar] = make_float2(m[qi], 1.0f / lsum[qi]);
    }
}

// ---------------- Pass B: recompute scores -> weights (HBM) + PV -> attn0 ----------------
__global__ __launch_bounds__(256) void fused_pv_kernel(const _Float16* __restrict__ Q,
                                                       const _Float16* __restrict__ Kmat,
                                                       const _Float16* __restrict__ Vt,
                                                       const float* __restrict__ lut,
                                                       const int* __restrict__ mask,
                                                       const float2* __restrict__ stats,
                                                       float* __restrict__ wts,
                                                       _Float16* __restrict__ attn0) {
    __shared__ _Float16 Pl[4][32][72];   // per-wave P staging, padded row (144 B)
    int l = threadIdx.x & 63, w = threadIdx.x >> 6;
    int bh = blockIdx.y;
    int b = bh >> 4, h = bh & 15;
    int qbase = blockIdx.x * 128 + w * 32;
    size_t hoff = (size_t)(b * SEQ) * DMODEL + h * HEADD;
    int ar = l & 15, g = l >> 4, ak = g * 8;
    const float* luth = lut + h * LUTW;
    float* ob = wts + (size_t)bh * SEQ * SEQ;

    half8 qf[2][2];
#pragma unroll
    for (int qi = 0; qi < 2; qi++)
#pragma unroll
        for (int kk = 0; kk < 2; kk++)
            qf[qi][kk] = *(const half8*)(Q + hoff + (size_t)(qbase + qi * 16 + ar) * DMODEL + kk * 32 + ak);
    float2 st[2];
#pragma unroll
    for (int qi = 0; qi < 2; qi++) st[qi] = stats[bh * SEQ + qbase + qi * 16 + ar];

    f32x4 oacc[2][4] = {};

    for (int k0 = 0; k0 < SEQ; k0 += 64) {
        half8 kf[4][2];
#pragma unroll
        for (int ni = 0; ni < 4; ni++)
#pragma unroll
            for (int kk = 0; kk < 2; kk++)
                kf[ni][kk] = *(const half8*)(Kmat + hoff + (size_t)(k0 + ni * 16 + ar) * DMODEL + kk * 32 + ak);
        f32x4 acc[4][2] = {};
#pragma unroll
        for (int ni = 0; ni < 4; ni++)
#pragma unroll
            for (int qi = 0; qi < 2; qi++)
#pragma unroll
                for (int kk = 0; kk < 2; kk++)
                    acc[ni][qi] = __builtin_amdgcn_mfma_f32_16x16x32_f16(kf[ni][kk], qf[qi][kk], acc[ni][qi], 0, 0, 0);
        int4 mk[4];
#pragma unroll
        for (int ni = 0; ni < 4; ni++)
            mk[ni] = *(const int4*)(mask + b * SEQ + k0 + ni * 16 + g * 4);
#pragma unroll
        for (int ni = 0; ni < 4; ni++) {
            const int* mp = (const int*)&mk[ni];
#pragma unroll
            for (int qi = 0; qi < 2; qi++) {
                int q = qbase + qi * 16 + ar;
                f32x4 wv;
#pragma unroll
                for (int j = 0; j < 4; j++) {
                    int k = k0 + ni * 16 + g * 4 + j;
                    float v = mp[j] ? (acc[ni][qi][j] + luth[k - q + 2047]) : -1e9f;
                    wv[j] = __expf(v - st[qi].x) * st[qi].y;
                }
                *(f32x4*)(ob + (size_t)q * SEQ + k0 + ni * 16 + g * 4) = wv;
                half4 ph;
#pragma unroll
                for (int j = 0; j < 4; j++) ph[j] = (_Float16)wv[j];
                *(half4*)&Pl[w][qi * 16 + ar][ni * 16 + g * 4] = ph;
            }
        }
        // PV: O[q,hd] += P[q,s] * Vt[hd,s]
#pragma unroll
        for (int kk2 = 0; kk2 < 2; kk2++) {
            half8 pa[2];
#pragma unroll
            for (int qi = 0; qi < 2; qi++)
                pa[qi] = *(half8*)&Pl[w][qi * 16 + ar][kk2 * 32 + g * 8];
#pragma unroll
            for (int ni = 0; ni < 4; ni++) {
                half8 vf = *(const half8*)(Vt + ((size_t)bh * HEADD + ni * 16 + ar) * SEQ + k0 + kk2 * 32 + g * 8);
#pragma unroll
                for (int qi = 0; qi < 2; qi++)
                    oacc[qi][ni] = __builtin_amdgcn_mfma_f32_16x16x32_f16(pa[qi], vf, oacc[qi][ni], 0, 0, 0);
            }
        }
    }
#pragma unroll
    for (int qi = 0; qi < 2; qi++)
#pragma unroll
        for (int ni = 0; ni < 4; ni++)
#pragma unroll
            for (int j = 0; j < 4; j++)
                attn0[(size_t)(b * SEQ + qbase + qi * 16 + g * 4 + j) * DMODEL + h * HEADD + ni * 16 + ar] =
                    (_Float16)oacc[qi][ni][j];
}

extern "C" void kernel_launch(void* const* d_in, const int* in_sizes, int n_in,
                              void* d_out, int out_size, void* d_ws, size_t ws_size,
                              hipStream_t stream) {
    const float* hs = (const float*)d_in[0];
    const int* mask = (const int*)d_in[1];
    const float* Wq = (const float*)d_in[2];
    const float* Wk = (const float*)d_in[3];
    const float* Wv = (const float*)d_in[4];
    const float* Wo = (const float*)d_in[5];
    const float* rel_bias = (const float*)d_in[6];

    float* out_attn = (float*)d_out;                       // [2,2048,1024]
    float* out_wts = out_attn + (size_t)2 * SEQ * DMODEL;  // [2,16,2048,2048]
    float* out_posb = out_wts + (size_t)NBH * SEQ * SEQ;   // [1,16,2048,2048]

    char* ws = (char*)d_ws;
    size_t off = 0;
    auto carve = [&](size_t bytes) { void* p = ws + off; off += (bytes + 255) & ~(size_t)255; return p; };
    _Float16* Xh  = (_Float16*)carve((size_t)2 * SEQ * DMODEL * 2);
    _Float16* Wqh = (_Float16*)carve((size_t)DMODEL * DMODEL * 2);
    _Float16* Wkh = (_Float16*)carve((size_t)DMODEL * DMODEL * 2);
    _Float16* Wvh = (_Float16*)carve((size_t)DMODEL * DMODEL * 2);
    _Float16* Woh = (_Float16*)carve((size_t)DMODEL * DMODEL * 2);
    _Float16* Qh  = (_Float16*)carve((size_t)2 * SEQ * DMODEL * 2);
    _Float16* Kh  = (_Float16*)carve((size_t)2 * SEQ * DMODEL * 2);
    _Float16* Vt  = (_Float16*)carve((size_t)NBH * HEADD * SEQ * 2);
    _Float16* A0h = (_Float16*)carve((size_t)2 * SEQ * DMODEL * 2);
    float* lut    = (float*)carve((size_t)NHEAD * LUTW * 4);
    float2* stats = (float2*)carve((size_t)NBH * SEQ * 8);

    int nX = 2 * SEQ * DMODEL;   // 4194304
    int nW = DMODEL * DMODEL;    // 1048576

    cast_h_kernel<<<nX / 8 / 256, 256, 0, stream>>>(hs, Xh, nX);
    cast_h_kernel<<<nW / 8 / 256, 256, 0, stream>>>(Wq, Wqh, nW);
    cast_h_kernel<<<nW / 8 / 256, 256, 0, stream>>>(Wk, Wkh, nW);
    cast_h_kernel<<<nW / 8 / 256, 256, 0, stream>>>(Wv, Wvh, nW);
    cast_h_kernel<<<nW / 8 / 256, 256, 0, stream>>>(Wo, Woh, nW);
    biaslut_kernel<<<NHEAD * LUTW / 256, 256, 0, stream>>>(rel_bias, lut);

    // projections: M=4096, N=1024, K=1024
    dim3 pg(DMODEL / 128, (2 * SEQ) / 128);
    gemm_bt_h_kernel<<<pg, 256, 0, stream>>>(Xh, Wqh, Qh, 2 * SEQ, DMODEL, DMODEL, 0);
    gemm_bt_h_kernel<<<pg, 256, 0, stream>>>(Xh, Wkh, Kh, 2 * SEQ, DMODEL, DMODEL, 0);
    gemm_bt_h_kernel<<<pg, 256, 0, stream>>>(Xh, Wvh, Vt, 2 * SEQ, DMODEL, DMODEL, 1);

    // position bias output
    posbias_kernel<<<(NHEAD * SEQ * SEQ / 4) / 256, 256, 0, stream>>>(lut, out_posb);

    // pass A: per-row softmax stats (no score write)
    dim3 ag(SEQ / 128, NBH);
    stats_kernel<<<ag, 256, 0, stream>>>(Qh, Kh, lut, mask, stats);

    // pass B: recompute scores -> final weights + PV
    fused_pv_kernel<<<ag, 256, 0, stream>>>(Qh, Kh, Vt, lut, mask, stats, out_wts, A0h);

    // final projection -> out_attn (fp32)
    gemm_bt_h_kernel<<<pg, 256, 0, stream>>>(A0h, Woh, out_attn, 2 * SEQ, DMODEL, DMODEL, 2);
}

// Round 5
// 615.778 us; speedup vs baseline: 1.7187x; 1.2753x over previous
//
#include <hip/hip_runtime.h>

typedef __attribute__((ext_vector_type(8))) _Float16 half8;
typedef __attribute__((ext_vector_type(4))) _Float16 half4;
typedef __attribute__((ext_vector_type(4))) float f32x4;

#define SEQ 2048
#define DMODEL 1024
#define NHEAD 16
#define HEADD 64
#define NBH 32          // B * NHEAD
#define LUTW 4096

__device__ __forceinline__ void nt_store_f4(float* p, f32x4 v) {
    __builtin_nontemporal_store(v, (f32x4*)p);
}

// ---------------- T5 relative position bucket ----------------
__device__ __forceinline__ int rel_bucket(int rel) {
    int ret = (rel > 0) ? 16 : 0;
    int rp = rel < 0 ? -rel : rel;
    if (rp < 8) return ret + rp;
    float x = logf((float)rp * 0.125f) / 2.7725887f * 8.0f;
    int v = 8 + (int)x;
    v = v < 15 ? v : 15;
    return ret + v;
}

// ---------------- prep: all casts + bias LUT in one launch ----------------
// blocks 0..2047       : X cast        (4194304 elems, 8/thread)
// blocks 2048..2559    : Wq cast       (1048576 elems)
// blocks 2560..3071    : Wk cast
// blocks 3072..3583    : Wv cast
// blocks 3584..4095    : Wo cast
// blocks 4096..4351    : lut build     (65536 entries, 1/thread)
__global__ __launch_bounds__(256) void prep_kernel(const float* __restrict__ hs,
                                                   const float* __restrict__ Wq,
                                                   const float* __restrict__ Wk,
                                                   const float* __restrict__ Wv,
                                                   const float* __restrict__ Wo,
                                                   const float* __restrict__ rel_bias,
                                                   _Float16* __restrict__ Xh,
                                                   _Float16* __restrict__ Wqh,
                                                   _Float16* __restrict__ Wkh,
                                                   _Float16* __restrict__ Wvh,
                                                   _Float16* __restrict__ Woh,
                                                   float* __restrict__ lut) {
    int bid = blockIdx.x;
    if (bid < 4096) {
        const float* in;
        _Float16* out;
        int base;
        if (bid < 2048)      { in = hs; out = Xh;  base = bid; }
        else if (bid < 2560) { in = Wq; out = Wqh; base = bid - 2048; }
        else if (bid < 3072) { in = Wk; out = Wkh; base = bid - 2560; }
        else if (bid < 3584) { in = Wv; out = Wvh; base = bid - 3072; }
        else                 { in = Wo; out = Woh; base = bid - 3584; }
        int i = (base * 256 + threadIdx.x) * 8;
        f32x4 a = *(const f32x4*)(in + i);
        f32x4 b = *(const f32x4*)(in + i + 4);
        half8 r;
        r[0] = (_Float16)a[0]; r[1] = (_Float16)a[1];
        r[2] = (_Float16)a[2]; r[3] = (_Float16)a[3];
        r[4] = (_Float16)b[0]; r[5] = (_Float16)b[1];
        r[6] = (_Float16)b[2]; r[7] = (_Float16)b[3];
        *(half8*)(out + i) = r;
    } else {
        int i = (bid - 4096) * 256 + threadIdx.x;   // 16 * 4096
        int h = i >> 12;
        int idx = i & (LUTW - 1);
        int rel = idx - 2047;
        int b = rel_bucket(rel);
        lut[i] = rel_bias[b * NHEAD + h];
    }
}

// ---------------- fused Q/K/V projection: z = 0(Q) 1(K) 2(V->Vt) ----------------
__global__ __launch_bounds__(256) void proj3_kernel(const _Float16* __restrict__ Xh,
                                                    const _Float16* __restrict__ Wqh,
                                                    const _Float16* __restrict__ Wkh,
                                                    const _Float16* __restrict__ Wvh,
                                                    _Float16* __restrict__ Qh,
                                                    _Float16* __restrict__ Kh,
                                                    _Float16* __restrict__ Vt) {
    int z = blockIdx.z;
    const _Float16* B = (z == 0) ? Wqh : (z == 1) ? Wkh : Wvh;
    int l = threadIdx.x & 63, w = threadIdx.x >> 6;
    int row0 = blockIdx.y * 128 + (w >> 1) * 64;
    int col0 = blockIdx.x * 128 + (w & 1) * 64;
    int ar = l & 15, ak = (l >> 4) * 8;
    f32x4 acc[4][4] = {};
    for (int k0 = 0; k0 < DMODEL; k0 += 32) {
        half8 af[4], bf[4];
#pragma unroll
        for (int mi = 0; mi < 4; mi++)
            af[mi] = *(const half8*)(Xh + (size_t)(row0 + mi * 16 + ar) * DMODEL + k0 + ak);
#pragma unroll
        for (int ni = 0; ni < 4; ni++)
            bf[ni] = *(const half8*)(B + (size_t)(col0 + ni * 16 + ar) * DMODEL + k0 + ak);
#pragma unroll
        for (int mi = 0; mi < 4; mi++)
#pragma unroll
            for (int ni = 0; ni < 4; ni++)
                acc[mi][ni] = __builtin_amdgcn_mfma_f32_16x16x32_f16(af[mi], bf[ni], acc[mi][ni], 0, 0, 0);
    }
    int cr = (l >> 4) * 4, cc = l & 15;
    if (z < 2) {
        _Float16* C = z == 0 ? Qh : Kh;
#pragma unroll
        for (int mi = 0; mi < 4; mi++)
#pragma unroll
            for (int ni = 0; ni < 4; ni++) {
                int c = col0 + ni * 16 + cc;
#pragma unroll
                for (int j = 0; j < 4; j++)
                    C[(size_t)(row0 + mi * 16 + cr + j) * DMODEL + c] = (_Float16)acc[mi][ni][j];
            }
    } else {
#pragma unroll
        for (int mi = 0; mi < 4; mi++)
#pragma unroll
            for (int ni = 0; ni < 4; ni++) {
                int c = col0 + ni * 16 + cc;
                int h = c >> 6, hd = c & 63;
                int r = row0 + mi * 16 + cr;
                int b = r >> 11, s0 = r & 2047;
                half4 pk;
#pragma unroll
                for (int j = 0; j < 4; j++) pk[j] = (_Float16)acc[mi][ni][j];
                *(half4*)(Vt + (size_t)((b * NHEAD + h) * HEADD + hd) * SEQ + s0) = pk;
            }
    }
}

// ---------------- fused attention: stats (phase1) + weights/posbias/PV (phase2) ----------------
__global__ __launch_bounds__(256) void attn_kernel(const _Float16* __restrict__ Q,
                                                   const _Float16* __restrict__ Kmat,
                                                   const _Float16* __restrict__ Vt,
                                                   const float* __restrict__ lut,
                                                   const int* __restrict__ mask,
                                                   float* __restrict__ wts,
                                                   float* __restrict__ posb,
                                                   _Float16* __restrict__ attn0) {
    __shared__ _Float16 Pl[4][32][72];   // per-wave P staging, padded
    int l = threadIdx.x & 63, w = threadIdx.x >> 6;
    int bh = blockIdx.y;
    int b = bh >> 4, h = bh & 15;
    int qbase = blockIdx.x * 128 + w * 32;
    size_t hoff = (size_t)(b * SEQ) * DMODEL + h * HEADD;
    int ar = l & 15, g = l >> 4, ak = g * 8;
    const float* luth = lut + h * LUTW;
    float* ob = wts + (size_t)bh * SEQ * SEQ;

    half8 qf[2][2];
#pragma unroll
    for (int qi = 0; qi < 2; qi++)
#pragma unroll
        for (int kk = 0; kk < 2; kk++)
            qf[qi][kk] = *(const half8*)(Q + hoff + (size_t)(qbase + qi * 16 + ar) * DMODEL + kk * 32 + ak);

    // ---------- phase 1: online per-row stats ----------
    float m[2] = {-3e38f, -3e38f};
    float lsum[2] = {0.f, 0.f};
    for (int k0 = 0; k0 < SEQ; k0 += 64) {
        half8 kf[4][2];
#pragma unroll
        for (int ni = 0; ni < 4; ni++)
#pragma unroll
            for (int kk = 0; kk < 2; kk++)
                kf[ni][kk] = *(const half8*)(Kmat + hoff + (size_t)(k0 + ni * 16 + ar) * DMODEL + kk * 32 + ak);
        f32x4 acc[4][2] = {};
#pragma unroll
        for (int ni = 0; ni < 4; ni++)
#pragma unroll
            for (int qi = 0; qi < 2; qi++)
#pragma unroll
                for (int kk = 0; kk < 2; kk++)
                    acc[ni][qi] = __builtin_amdgcn_mfma_f32_16x16x32_f16(kf[ni][kk], qf[qi][kk], acc[ni][qi], 0, 0, 0);
        int4 mk[4];
#pragma unroll
        for (int ni = 0; ni < 4; ni++)
            mk[ni] = *(const int4*)(mask + b * SEQ + k0 + ni * 16 + g * 4);
#pragma unroll
        for (int qi = 0; qi < 2; qi++) {
            int q = qbase + qi * 16 + ar;
            float vv[16];
            float vmax = -3e38f;
#pragma unroll
            for (int ni = 0; ni < 4; ni++) {
                const int* mp = (const int*)&mk[ni];
#pragma unroll
                for (int j = 0; j < 4; j++) {
                    int k = k0 + ni * 16 + g * 4 + j;
                    float v = mp[j] ? (acc[ni][qi][j] + luth[k - q + 2047]) : -1e9f;
                    vv[ni * 4 + j] = v;
                    vmax = fmaxf(vmax, v);
                }
            }
            float mn = fmaxf(m[qi], vmax);
            float scale = __expf(m[qi] - mn);
            float s = 0.f;
#pragma unroll
            for (int t = 0; t < 16; t++) s += __expf(vv[t] - mn);
            lsum[qi] = lsum[qi] * scale + s;
            m[qi] = mn;
        }
    }
    float invl[2];
#pragma unroll
    for (int qi = 0; qi < 2; qi++) {
#pragma unroll
        for (int off = 16; off <= 32; off <<= 1) {
            float mo = __shfl_xor(m[qi], off);
            float lo = __shfl_xor(lsum[qi], off);
            float mn = fmaxf(m[qi], mo);
            lsum[qi] = lsum[qi] * __expf(m[qi] - mn) + lo * __expf(mo - mn);
            m[qi] = mn;
        }
        invl[qi] = 1.0f / lsum[qi];
    }

    // ---------- phase 2: recompute -> weights (+posbias) + PV ----------
    f32x4 oacc[2][4] = {};
    for (int k0 = 0; k0 < SEQ; k0 += 64) {
        half8 kf[4][2];
#pragma unroll
        for (int ni = 0; ni < 4; ni++)
#pragma unroll
            for (int kk = 0; kk < 2; kk++)
                kf[ni][kk] = *(const half8*)(Kmat + hoff + (size_t)(k0 + ni * 16 + ar) * DMODEL + kk * 32 + ak);
        f32x4 acc[4][2] = {};
#pragma unroll
        for (int ni = 0; ni < 4; ni++)
#pragma unroll
            for (int qi = 0; qi < 2; qi++)
#pragma unroll
                for (int kk = 0; kk < 2; kk++)
                    acc[ni][qi] = __builtin_amdgcn_mfma_f32_16x16x32_f16(kf[ni][kk], qf[qi][kk], acc[ni][qi], 0, 0, 0);
        int4 mk[4];
#pragma unroll
        for (int ni = 0; ni < 4; ni++)
            mk[ni] = *(const int4*)(mask + b * SEQ + k0 + ni * 16 + g * 4);
#pragma unroll
        for (int ni = 0; ni < 4; ni++) {
            const int* mp = (const int*)&mk[ni];
            int kcol = k0 + ni * 16 + g * 4;
#pragma unroll
            for (int qi = 0; qi < 2; qi++) {
                int q = qbase + qi * 16 + ar;
                f32x4 wv, pb;
#pragma unroll
                for (int j = 0; j < 4; j++) {
                    float lb = luth[kcol + j - q + 2047];
                    pb[j] = lb;
                    float v = mp[j] ? (acc[ni][qi][j] + lb) : -1e9f;
                    wv[j] = __expf(v - m[qi]) * invl[qi];
                }
                nt_store_f4(ob + (size_t)q * SEQ + kcol, wv);
                if (b == 0)
                    nt_store_f4(posb + (size_t)h * SEQ * SEQ + (size_t)q * SEQ + kcol, pb);
                half4 ph;
#pragma unroll
                for (int j = 0; j < 4; j++) ph[j] = (_Float16)wv[j];
                *(half4*)&Pl[w][qi * 16 + ar][ni * 16 + g * 4] = ph;
            }
        }
        // PV: O[q,hd] += P[q,s] * Vt[hd,s]
#pragma unroll
        for (int kk2 = 0; kk2 < 2; kk2++) {
            half8 pa[2];
#pragma unroll
            for (int qi = 0; qi < 2; qi++)
                pa[qi] = *(half8*)&Pl[w][qi * 16 + ar][kk2 * 32 + g * 8];
#pragma unroll
            for (int ni = 0; ni < 4; ni++) {
                half8 vf = *(const half8*)(Vt + ((size_t)bh * HEADD + ni * 16 + ar) * SEQ + k0 + kk2 * 32 + g * 8);
#pragma unroll
                for (int qi = 0; qi < 2; qi++)
                    oacc[qi][ni] = __builtin_amdgcn_mfma_f32_16x16x32_f16(pa[qi], vf, oacc[qi][ni], 0, 0, 0);
            }
        }
    }
#pragma unroll
    for (int qi = 0; qi < 2; qi++)
#pragma unroll
        for (int ni = 0; ni < 4; ni++)
#pragma unroll
            for (int j = 0; j < 4; j++)
                attn0[(size_t)(b * SEQ + qbase + qi * 16 + g * 4 + j) * DMODEL + h * HEADD + ni * 16 + ar] =
                    (_Float16)oacc[qi][ni][j];
}

// ---------------- output projection: C fp32 = A0h * Woh^T ----------------
__global__ __launch_bounds__(256) void outgemm_kernel(const _Float16* __restrict__ A,
                                                      const _Float16* __restrict__ B,
                                                      float* __restrict__ C) {
    int l = threadIdx.x & 63, w = threadIdx.x >> 6;
    int row0 = blockIdx.y * 128 + (w >> 1) * 64;
    int col0 = blockIdx.x * 128 + (w & 1) * 64;
    int ar = l & 15, ak = (l >> 4) * 8;
    f32x4 acc[4][4] = {};
    for (int k0 = 0; k0 < DMODEL; k0 += 32) {
        half8 af[4], bf[4];
#pragma unroll
        for (int mi = 0; mi < 4; mi++)
            af[mi] = *(const half8*)(A + (size_t)(row0 + mi * 16 + ar) * DMODEL + k0 + ak);
#pragma unroll
        for (int ni = 0; ni < 4; ni++)
            bf[ni] = *(const half8*)(B + (size_t)(col0 + ni * 16 + ar) * DMODEL + k0 + ak);
#pragma unroll
        for (int mi = 0; mi < 4; mi++)
#pragma unroll
            for (int ni = 0; ni < 4; ni++)
                acc[mi][ni] = __builtin_amdgcn_mfma_f32_16x16x32_f16(af[mi], bf[ni], acc[mi][ni], 0, 0, 0);
    }
    int cr = (l >> 4) * 4, cc = l & 15;
#pragma unroll
    for (int mi = 0; mi < 4; mi++)
#pragma unroll
        for (int ni = 0; ni < 4; ni++) {
            int c = col0 + ni * 16 + cc;
#pragma unroll
            for (int j = 0; j < 4; j++)
                C[(size_t)(row0 + mi * 16 + cr + j) * DMODEL + c] = acc[mi][ni][j];
        }
}

extern "C" void kernel_launch(void* const* d_in, const int* in_sizes, int n_in,
                              void* d_out, int out_size, void* d_ws, size_t ws_size,
                              hipStream_t stream) {
    const float* hs = (const float*)d_in[0];
    const int* mask = (const int*)d_in[1];
    const float* Wq = (const float*)d_in[2];
    const float* Wk = (const float*)d_in[3];
    const float* Wv = (const float*)d_in[4];
    const float* Wo = (const float*)d_in[5];
    const float* rel_bias = (const float*)d_in[6];

    float* out_attn = (float*)d_out;                       // [2,2048,1024]
    float* out_wts = out_attn + (size_t)2 * SEQ * DMODEL;  // [2,16,2048,2048]
    float* out_posb = out_wts + (size_t)NBH * SEQ * SEQ;   // [1,16,2048,2048]

    char* ws = (char*)d_ws;
    size_t off = 0;
    auto carve = [&](size_t bytes) { void* p = ws + off; off += (bytes + 255) & ~(size_t)255; return p; };
    _Float16* Xh  = (_Float16*)carve((size_t)2 * SEQ * DMODEL * 2);
    _Float16* Wqh = (_Float16*)carve((size_t)DMODEL * DMODEL * 2);
    _Float16* Wkh = (_Float16*)carve((size_t)DMODEL * DMODEL * 2);
    _Float16* Wvh = (_Float16*)carve((size_t)DMODEL * DMODEL * 2);
    _Float16* Woh = (_Float16*)carve((size_t)DMODEL * DMODEL * 2);
    _Float16* Qh  = (_Float16*)carve((size_t)2 * SEQ * DMODEL * 2);
    _Float16* Kh  = (_Float16*)carve((size_t)2 * SEQ * DMODEL * 2);
    _Float16* Vt  = (_Float16*)carve((size_t)NBH * HEADD * SEQ * 2);
    _Float16* A0h = (_Float16*)carve((size_t)2 * SEQ * DMODEL * 2);
    float* lut    = (float*)carve((size_t)NHEAD * LUTW * 4);

    // 1. prep: casts + lut
    prep_kernel<<<4352, 256, 0, stream>>>(hs, Wq, Wk, Wv, Wo, rel_bias,
                                          Xh, Wqh, Wkh, Wvh, Woh, lut);

    // 2. Q/K/V projections in one launch (3 blocks/CU)
    dim3 pg(DMODEL / 128, (2 * SEQ) / 128, 3);
    proj3_kernel<<<pg, 256, 0, stream>>>(Xh, Wqh, Wkh, Wvh, Qh, Kh, Vt);

    // 3. fused attention: stats + weights + posbias + PV
    dim3 ag(SEQ / 128, NBH);
    attn_kernel<<<ag, 256, 0, stream>>>(Qh, Kh, Vt, lut, mask, out_wts, out_posb, A0h);

    // 4. output projection
    dim3 og(DMODEL / 128, (2 * SEQ) / 128);
    outgemm_kernel<<<og, 256, 0, stream>>>(A0h, Woh, out_attn);
}